// Round 5
// baseline (801.993 us; speedup 1.0000x reference)
//
#include <hip/hip_runtime.h>
#include <stdint.h>

#define N_NODES 100000
#define N_EDGES 1000000
#define DIM 256
#define CAP 32            // fixed neighbor-slot capacity per node (Poisson(10) graph)

typedef __attribute__((ext_vector_type(8))) short short8;          // bf16 MFMA frag (4 VGPR)
typedef __attribute__((ext_vector_type(8))) unsigned short u16x8;  // 16B row chunk
typedef __attribute__((ext_vector_type(4))) float f32x4;           // fp32 C/D frag / NT ops
typedef __attribute__((ext_vector_type(4))) unsigned short u16x4;  // 8B bf16 store

__device__ inline float b2f(unsigned short u) {
    union { unsigned int i; float f; } v; v.i = ((unsigned int)u) << 16; return v.f;
}
__device__ inline unsigned short f2b(float f) {   // round-to-nearest-even
    union { float f; unsigned int i; } v; v.f = f;
    unsigned int u = v.i;
    return (unsigned short)((u + 0x7FFFu + ((u >> 16) & 1u)) >> 16);
}

// ---------------- workspace layout (bytes) ----------------
// cnt    u32 N          @ 0          (raw in-degree; may exceed CAP)
// ovfCnt u32            @ 400000
// colM   i32 N*CAP      @ 400256     (12.8 MB; zeroed: tail slots -> idx 0, w=0)
// wgt    f32 N          @ 13200256   (rsqrt(cnt+1), precomputed once)
// ovf    u32 pairs E    @ 13600256   (8 MB: worst-case-correct overflow list)
// Wt1    bf16 256x256   @ 21600256   (n-major, k contiguous)
// Wt2    bf16 256x256   @ 21731328
// xs     bf16 N*256     @ 21862400   (raw bf16 features, NOT prescaled)
// z1s    bf16 N*256     @ 73062400   (raw bf16 layer-1 relu output)
// memset range [0, 13200256) covers cnt | ovfCnt | colM in one shot.

#define NB_FILL 3907   // (1M+255)/256 edge blocks
#define NB_PACK 512
#define NB_CVT  25000  // N*256/4 float4 elems / 256 threads

// ONE preprocessing kernel: bucket-fill (blocks [0,3907), latency/atomic-bound,
// dispatched first) + W1/W2 pack + x->bf16 convert (BW-bound, overlaps fill).
__global__ void k_pre(const int* __restrict__ src, const int* __restrict__ dst,
                      uint32_t* __restrict__ cnt, uint32_t* __restrict__ ovfCnt,
                      int* __restrict__ colM, uint32_t* __restrict__ ovf,
                      const float* __restrict__ W1, const float* __restrict__ W2,
                      unsigned short* __restrict__ Wt1, unsigned short* __restrict__ Wt2,
                      const float* __restrict__ x, unsigned short* __restrict__ xs) {
    int b = blockIdx.x, t = threadIdx.x;
    if (b < NB_FILL) {
        int e = b * 256 + t;
        if (e < N_EDGES) {
            unsigned d = (unsigned)dst[e];
            unsigned s = (unsigned)src[e];
            if (d < N_NODES && s < N_NODES) {
                uint32_t p = atomicAdd(&cnt[d], 1u);
                if (p < CAP) colM[(size_t)d * CAP + p] = (int)s;
                else {       // correctness fallback; statistically never taken
                    uint32_t o = atomicAdd(ovfCnt, 1u);
                    if (o < (uint32_t)N_EDGES) { ovf[2 * o] = d; ovf[2 * o + 1] = s; }
                }
            }
        }
    } else if (b < NB_FILL + NB_PACK) {
        int n = b - NB_FILL;
        if (n < 256) Wt1[n * 256 + t] = f2b(W1[t * 256 + n]);
        else { n -= 256; Wt2[n * 256 + t] = f2b(W2[t * 256 + n]); }
    } else {
        int i = (b - (NB_FILL + NB_PACK)) * 256 + t;   // float4 index, exactly N*64
        f32x4 v = __builtin_nontemporal_load((const f32x4*)x + i);  // read-once stream
        u16x4 o;
        o.x = f2b(v.x); o.y = f2b(v.y); o.z = f2b(v.z); o.w = f2b(v.w);
        *((u16x4*)xs + i) = o;                          // re-read by gather -> cacheable
    }
}

// wgt[n] = rsqrt(cnt[n]+1): hoists the per-edge int->float + rsqrt out of the
// gather hot loop.
__global__ void k_wgt(const uint32_t* __restrict__ cnt, float* __restrict__ wgt) {
    int n = blockIdx.x * blockDim.x + threadIdx.x;
    if (n < N_NODES) wgt[n] = rsqrtf((float)(cnt[n] + 1u));
}

// Fused gather + GEMM per 64-node block — 512 threads / 8 WAVES.
//
// Round-4 post-mortem: gather BW scaled ~linearly with resident waves across
// three rounds (1.9 -> 2.4 -> 3.6 TB/s) and nothing else is near a limit
// (MfmaUtil 4%, VALU 28%, regs at half budget). So double concurrency:
// LDS stays 32768 B -> 4 blocks/CU, now 8 waves each = 32 waves/CU nominal
// (100% occupancy cap) vs 16 before. Each wave gathers 8 nodes (4 half-wave
// pairs), halving the per-wave serial chain; GEMM splits into 2 row-groups x
// 4 col-groups (acc = 32 AGPR/wave).
//
// Phase 1 (gather): lanes 0-31 = node A, 32-63 = node B, 16 B/lane. Inner
// loop is BRANCHLESS and 8-wide: one int4 pair loads 8 neighbor indices from
// colM, then 8 independent 16B row loads + 8 broadcast wgt loads issue
// back-to-back (8 KB in flight per wave). Tail slots: zeroed colM -> idx 0,
// w=0 (mask for free). Rows land in the XOR-swizzled LDS A-tile.
//
// Phase 2 (GEMM, swapped operands): acc = mfma(Wt_frag, A_frag, acc) computes
// C^T in-register: D row = output COLUMN -> float4/ushort4 vector stores.
__global__ __launch_bounds__(512, 8) void k_fused(
        const unsigned short* __restrict__ rows, const uint32_t* __restrict__ cnt,
        const float* __restrict__ wgt,
        const uint32_t* __restrict__ ovfCnt, const int* __restrict__ colM,
        const uint32_t* __restrict__ ovf, const unsigned short* __restrict__ Wt,
        const float* __restrict__ bias,
        unsigned short* __restrict__ Cb, float* __restrict__ Cf) {
    __shared__ __align__(16) unsigned short As[64 * 256];   // 32768 B, swizzled

    int tid = threadIdx.x;
    int w = tid >> 6, lane = tid & 63;
    int hl = lane & 31, half = lane >> 5;
    int rowBase = blockIdx.x * 64;
    uint32_t ovfN = *ovfCnt;

    // ---- phase 1: gather 8 nodes/wave as 4 half-wave pairs ----
    const u16x8* r8 = (const u16x8*)rows;
    #pragma unroll 1
    for (int t = 0; t < 4; ++t) {
        int nl    = w * 8 + t * 2 + half;      // local row 0..63
        int node  = rowBase + nl;
        bool valid = node < N_NODES;
        int nsafe = valid ? node : 0;

        uint32_t dgRaw = cnt[nsafe];                    // true degree (may exceed CAP)
        float    di    = wgt[nsafe];                    // rsqrt(deg+1), precomputed
        uint32_t dg    = valid ? (dgRaw < CAP ? dgRaw : CAP) : 0u;
        float    wSelf = valid ? di : 0.f;

        u16x8 sv = r8[(size_t)nsafe * 32 + hl];         // self row (raw bf16)
        float a[8];
        #pragma unroll
        for (int i = 0; i < 8; ++i) a[i] = wSelf * b2f(sv[i]);

        uint32_t dgo   = (uint32_t)__shfl((int)dg, lane ^ 32);
        uint32_t dgMax = dg > dgo ? dg : dgo;
        const int* cp  = colM + (size_t)nsafe * CAP;

        for (uint32_t j = 0; j < dgMax; j += 8) {       // <=4 iters; no branches inside
            int4 i0 = *(const int4*)(cp + j);           // 8 indices (tail slots = 0)
            int4 i1 = *(const int4*)(cp + j + 4);
            u16x8 r0 = r8[(size_t)i0.x * 32 + hl];      // 8 independent 16B row loads
            u16x8 r1 = r8[(size_t)i0.y * 32 + hl];
            u16x8 r2 = r8[(size_t)i0.z * 32 + hl];
            u16x8 r3 = r8[(size_t)i0.w * 32 + hl];
            u16x8 r4 = r8[(size_t)i1.x * 32 + hl];
            u16x8 r5 = r8[(size_t)i1.y * 32 + hl];
            u16x8 r6 = r8[(size_t)i1.z * 32 + hl];
            u16x8 r7 = r8[(size_t)i1.w * 32 + hl];
            float w0 = (j + 0 < dg) ? wgt[i0.x] : 0.f;  // broadcast f32 loads
            float w1 = (j + 1 < dg) ? wgt[i0.y] : 0.f;
            float w2 = (j + 2 < dg) ? wgt[i0.z] : 0.f;
            float w3 = (j + 3 < dg) ? wgt[i0.w] : 0.f;
            float w4 = (j + 4 < dg) ? wgt[i1.x] : 0.f;
            float w5 = (j + 5 < dg) ? wgt[i1.y] : 0.f;
            float w6 = (j + 6 < dg) ? wgt[i1.z] : 0.f;
            float w7 = (j + 7 < dg) ? wgt[i1.w] : 0.f;
            #pragma unroll
            for (int i = 0; i < 8; ++i) {
                float s = fmaf(w0, b2f(r0[i]), a[i]);
                s = fmaf(w1, b2f(r1[i]), s);
                s = fmaf(w2, b2f(r2[i]), s);
                s = fmaf(w3, b2f(r3[i]), s);
                s = fmaf(w4, b2f(r4[i]), s);
                s = fmaf(w5, b2f(r5[i]), s);
                s = fmaf(w6, b2f(r6[i]), s);
                s = fmaf(w7, b2f(r7[i]), s);
                a[i] = s;
            }
        }

        if (ovfN) {   // correctness-only path; never taken for this graph
            for (uint32_t k = 0; k < ovfN; ++k) {
                uint32_t od = ovf[2 * k], os = ovf[2 * k + 1];
                if (valid && od == (uint32_t)node) {
                    float wv = wgt[os];
                    u16x8 rv = r8[(size_t)os * 32 + hl];
                    #pragma unroll
                    for (int i = 0; i < 8; ++i) a[i] = fmaf(wv, b2f(rv[i]), a[i]);
                }
            }
        }

        short8 o;
        #pragma unroll
        for (int i = 0; i < 8; ++i) o[i] = (short)f2b(di * a[i]);
        // swizzled write: logical chunk hl -> physical chunk hl ^ (row&7)
        *(short8*)((char*)As + nl * 512 + ((hl ^ (nl & 7)) << 4)) = o;
    }
    __syncthreads();

    // ---- phase 2: GEMM, swapped operands; wave = (rowGroup rg, colGroup cg) ----
    int m = lane & 15, quad = lane >> 4;
    int cg = w & 3;        // cols [cg*64, cg*64+64)
    int rg = w >> 2;       // rows [rg*32, rg*32+32)

    f32x4 acc[2][4];
    #pragma unroll
    for (int mt = 0; mt < 2; ++mt)
        #pragma unroll
        for (int nt = 0; nt < 4; ++nt)
            acc[mt][nt] = (f32x4){0.f, 0.f, 0.f, 0.f};

    #pragma unroll
    for (int ks = 0; ks < 8; ++ks) {          // K = 8 steps x 32
        short8 wf[4], xf[2];
        #pragma unroll
        for (int nt = 0; nt < 4; ++nt)
            wf[nt] = *(const short8*)(Wt + (size_t)(cg * 64 + nt * 16 + m) * 256 + ks * 32 + quad * 8);
        #pragma unroll
        for (int mt = 0; mt < 2; ++mt) {
            int rl = rg * 32 + mt * 16 + m;
            int ch = (ks * 4 + quad) ^ (rl & 7);
            xf[mt] = *(const short8*)((const char*)As + rl * 512 + (ch << 4));
        }
        #pragma unroll
        for (int mt = 0; mt < 2; ++mt)
            #pragma unroll
            for (int nt = 0; nt < 4; ++nt)
                acc[mt][nt] = __builtin_amdgcn_mfma_f32_16x16x32_bf16(
                    wf[nt], xf[mt], acc[mt][nt], 0, 0, 0);
    }

    // epilogue: D row (quad*4+r) = output col, D col (lane&15) = node
    float4 bv[4];
    #pragma unroll
    for (int nt = 0; nt < 4; ++nt)
        bv[nt] = *(const float4*)(bias + cg * 64 + nt * 16 + quad * 4);

    #pragma unroll
    for (int mt = 0; mt < 2; ++mt) {
        int node = rowBase + rg * 32 + mt * 16 + m;
        if (node >= N_NODES) continue;
        if (Cf) {
            #pragma unroll
            for (int nt = 0; nt < 4; ++nt) {
                int c = cg * 64 + nt * 16 + quad * 4;
                f32x4 v = acc[mt][nt];
                f32x4 o;
                o.x = fmaxf(v[0] + bv[nt].x, 0.f);
                o.y = fmaxf(v[1] + bv[nt].y, 0.f);
                o.z = fmaxf(v[2] + bv[nt].z, 0.f);
                o.w = fmaxf(v[3] + bv[nt].w, 0.f);
                // final output never re-read -> NT store, keep caches for gather rows
                __builtin_nontemporal_store(o, (f32x4*)(Cf + (size_t)node * 256 + c));
            }
        } else {
            #pragma unroll
            for (int nt = 0; nt < 4; ++nt) {
                int c = cg * 64 + nt * 16 + quad * 4;
                f32x4 v = acc[mt][nt];
                u16x4 o;   // raw relu, bf16 (layer-2 gather applies weights itself)
                o.x = f2b(fmaxf(v[0] + bv[nt].x, 0.f));
                o.y = f2b(fmaxf(v[1] + bv[nt].y, 0.f));
                o.z = f2b(fmaxf(v[2] + bv[nt].z, 0.f));
                o.w = f2b(fmaxf(v[3] + bv[nt].w, 0.f));
                *(u16x4*)(Cb + (size_t)node * 256 + c) = o;
            }
        }
    }
}

extern "C" void kernel_launch(void* const* d_in, const int* in_sizes, int n_in,
                              void* d_out, int out_size, void* d_ws, size_t ws_size,
                              hipStream_t stream) {
    const int*   edge = (const int*)d_in[0];   // [2][E]: row0 = src, row1 = dst
    const float* x    = (const float*)d_in[1];
    const float* W1   = (const float*)d_in[2];
    const float* b1   = (const float*)d_in[3];
    const float* W2   = (const float*)d_in[4];
    const float* b2   = (const float*)d_in[5];
    float* out = (float*)d_out;

    char* ws = (char*)d_ws;
    uint32_t*       cnt    = (uint32_t*)(ws + 0);
    uint32_t*       ovfCnt = (uint32_t*)(ws + 400000);
    int*            colM   = (int*)     (ws + 400256);
    float*          wgt    = (float*)   (ws + 13200256);
    uint32_t*       ovf    = (uint32_t*)(ws + 13600256);
    unsigned short* Wt1    = (unsigned short*)(ws + 21600256);
    unsigned short* Wt2    = (unsigned short*)(ws + 21731328);
    unsigned short* xs     = (unsigned short*)(ws + 21862400);
    unsigned short* z1s    = (unsigned short*)(ws + 73062400ull);

    const int* src = edge;
    const int* dst = edge + N_EDGES;

    // zero cnt + ovfCnt + colM in one shot
    hipMemsetAsync(ws, 0, 13200256, stream);

    // all heavy preprocessing in one launch: fill || pack || cvt
    k_pre<<<NB_FILL + NB_PACK + NB_CVT, 256, 0, stream>>>(
        src, dst, cnt, ovfCnt, colM, ovf, W1, W2, Wt1, Wt2, x, xs);
    // tiny: per-node weight table
    k_wgt<<<(N_NODES + 255) / 256, 256, 0, stream>>>(cnt, wgt);

    // layer 1: fused gather+GEMM, writes raw relu bf16 z1s
    k_fused<<<(N_NODES + 63) / 64, 512, 0, stream>>>(
        xs, cnt, wgt, ovfCnt, colM, ovf, Wt1, b1, z1s, nullptr);
    // layer 2: fused gather+GEMM, writes fp32 output
    k_fused<<<(N_NODES + 63) / 64, 512, 0, stream>>>(
        z1s, cnt, wgt, ovfCnt, colM, ovf, Wt2, b2, nullptr, out);
}

// Round 6
// 437.940 us; speedup vs baseline: 1.8313x; 1.8313x over previous
//
#include <hip/hip_runtime.h>
#include <stdint.h>

#define N_NODES 100000
#define N_EDGES 1000000
#define DIM 256
#define CAP 32            // fixed neighbor-slot capacity per node (Poisson(10) graph)

typedef __attribute__((ext_vector_type(8))) short short8;          // bf16 MFMA frag (4 VGPR)
typedef __attribute__((ext_vector_type(8))) unsigned short u16x8;  // 16B row chunk
typedef __attribute__((ext_vector_type(4))) float f32x4;           // fp32 C/D frag / NT ops
typedef __attribute__((ext_vector_type(4))) unsigned short u16x4;  // 8B bf16 store

__device__ inline float b2f(unsigned short u) {
    union { unsigned int i; float f; } v; v.i = ((unsigned int)u) << 16; return v.f;
}
__device__ inline unsigned short f2b(float f) {   // round-to-nearest-even
    union { float f; unsigned int i; } v; v.f = f;
    unsigned int u = v.i;
    return (unsigned short)((u + 0x7FFFu + ((u >> 16) & 1u)) >> 16);
}

// ---------------- workspace layout (bytes) ----------------
// cnt    u32 N          @ 0          (raw in-degree; may exceed CAP)
// ovfCnt u32            @ 400000
// colM   i32 N*CAP      @ 400256     (12.8 MB; NOT zeroed — gather clamps indices)
// wgt    f32 N          @ 13200256   (rsqrt(cnt+1), precomputed once)
// ovf    u32 pairs E    @ 13600256   (8 MB: worst-case-correct overflow list)
// Wt1    bf16 256x256   @ 21600256   (n-major, k contiguous)
// Wt2    bf16 256x256   @ 21731328
// xs     bf16 N*256     @ 21862400   (raw bf16 features, NOT prescaled)
// z1s    bf16 N*256     @ 73062400   (raw bf16 layer-1 relu output)
// memset range [0, 400256) covers cnt | ovfCnt only.

#define NB_FILL 489    // (1M + 2047)/2048 blocks; 8 edges/thread (ILP-8 atomic chains)
#define NB_PACK 512
#define NB_CVT  25000  // N*256/4 float4 elems / 256 threads

// ONE preprocessing kernel: bucket-fill (blocks [0,489), latency/atomic-bound,
// 8 independent edges per thread to hide the atomicAdd round trip) + W1/W2
// pack + x->bf16 convert (BW-bound, overlaps fill).
__global__ void k_pre(const int* __restrict__ src, const int* __restrict__ dst,
                      uint32_t* __restrict__ cnt, uint32_t* __restrict__ ovfCnt,
                      int* __restrict__ colM, uint32_t* __restrict__ ovf,
                      const float* __restrict__ W1, const float* __restrict__ W2,
                      unsigned short* __restrict__ Wt1, unsigned short* __restrict__ Wt2,
                      const float* __restrict__ x, unsigned short* __restrict__ xs) {
    int b = blockIdx.x, t = threadIdx.x;
    if (b < NB_FILL) {
        int e = b * 2048 + t;
        #pragma unroll
        for (int k = 0; k < 8; ++k, e += 256) {   // 8 independent atomic chains
            if (e < N_EDGES) {
                unsigned d = (unsigned)dst[e];
                unsigned s = (unsigned)src[e];
                if (d < N_NODES && s < N_NODES) {
                    uint32_t p = atomicAdd(&cnt[d], 1u);
                    if (p < CAP) colM[(size_t)d * CAP + p] = (int)s;
                    else {       // correctness fallback; statistically never taken
                        uint32_t o = atomicAdd(ovfCnt, 1u);
                        if (o < (uint32_t)N_EDGES) { ovf[2 * o] = d; ovf[2 * o + 1] = s; }
                    }
                }
            }
        }
    } else if (b < NB_FILL + NB_PACK) {
        int n = b - NB_FILL;
        if (n < 256) Wt1[n * 256 + t] = f2b(W1[t * 256 + n]);
        else { n -= 256; Wt2[n * 256 + t] = f2b(W2[t * 256 + n]); }
    } else {
        int i = (b - (NB_FILL + NB_PACK)) * 256 + t;   // float4 index, exactly N*64
        f32x4 v = __builtin_nontemporal_load((const f32x4*)x + i);  // read-once stream
        u16x4 o;
        o.x = f2b(v.x); o.y = f2b(v.y); o.z = f2b(v.z); o.w = f2b(v.w);
        *((u16x4*)xs + i) = o;                          // re-read by gather -> cacheable
    }
}

// wgt[n] = rsqrt(cnt[n]+1): hoists the per-edge int->float + rsqrt out of the
// gather hot loop.
__global__ void k_wgt(const uint32_t* __restrict__ cnt, float* __restrict__ wgt) {
    int n = blockIdx.x * blockDim.x + threadIdx.x;
    if (n < N_NODES) wgt[n] = rsqrtf((float)(cnt[n] + 1u));
}

// Fused gather + GEMM per 64-node block (4 waves) — ROUND-4 CONFIGURATION.
// Register-bucket reality (rounds 3/5 post-mortems): occupancy steps at 64/128
// total regs/wave. This kernel needs 64 VGPR + 64 AGPR = the 128 bucket ->
// 4 waves/SIMD, 16 waves/CU. Boxing it into the 64 bucket (512,8) spilled
// (WRITE 560 MB scratch, 2.5x slower). Do NOT tighten launch_bounds.
//
// Phase 1 (gather): each wave owns 16 nodes as 8 half-wave PAIRS (lanes 0-31 =
// node A, 32-63 = node B, 16 B/lane). Inner loop is BRANCHLESS and 8-wide:
// one int4 pair loads 8 neighbor indices from colM, then 8 independent 16B
// row loads + 8 broadcast wgt loads issue back-to-back (8 KB in flight/wave).
// colM is NOT zeroed: raw indices are clamped with min(ix, N-1) so loads
// always hit real finite rows; the (j+i<dg ? w : 0) mask kills their
// contribution. Tail garbage therefore cannot produce NaN (0 * finite = 0).
//
// Phase 2 (GEMM, swapped operands): acc = mfma(Wt_frag, A_frag, acc) computes
// C^T in-register: D row = output COLUMN -> float4/ushort4 vector stores.
__global__ __launch_bounds__(256, 4) void k_fused(
        const unsigned short* __restrict__ rows, const uint32_t* __restrict__ cnt,
        const float* __restrict__ wgt,
        const uint32_t* __restrict__ ovfCnt, const int* __restrict__ colM,
        const uint32_t* __restrict__ ovf, const unsigned short* __restrict__ Wt,
        const float* __restrict__ bias,
        unsigned short* __restrict__ Cb, float* __restrict__ Cf) {
    __shared__ __align__(16) unsigned short As[64 * 256];   // 32768 B, swizzled

    int tid = threadIdx.x;
    int w = tid >> 6, lane = tid & 63;
    int hl = lane & 31, half = lane >> 5;
    int rowBase = blockIdx.x * 64;
    uint32_t ovfN = *ovfCnt;

    // ---- phase 1: gather 16 nodes/wave as 8 half-wave pairs ----
    const u16x8* r8 = (const u16x8*)rows;
    #pragma unroll 1
    for (int t = 0; t < 8; ++t) {
        int nl    = w * 16 + t * 2 + half;     // local row 0..63
        int node  = rowBase + nl;
        bool valid = node < N_NODES;
        int nsafe = valid ? node : 0;

        uint32_t dgRaw = cnt[nsafe];                    // true degree (may exceed CAP)
        float    di    = wgt[nsafe];                    // rsqrt(deg+1), precomputed
        uint32_t dg    = valid ? (dgRaw < CAP ? dgRaw : CAP) : 0u;
        float    wSelf = valid ? di : 0.f;

        u16x8 sv = r8[(size_t)nsafe * 32 + hl];         // self row (raw bf16)
        float a[8];
        #pragma unroll
        for (int i = 0; i < 8; ++i) a[i] = wSelf * b2f(sv[i]);

        uint32_t dgo   = (uint32_t)__shfl((int)dg, lane ^ 32);
        uint32_t dgMax = dg > dgo ? dg : dgo;
        const int* cp  = colM + (size_t)nsafe * CAP;

        for (uint32_t j = 0; j < dgMax; j += 8) {       // <=4 iters; no branches inside
            int4 i0 = *(const int4*)(cp + j);           // 8 raw indices (tail = garbage)
            int4 i1 = *(const int4*)(cp + j + 4);
            // clamp: garbage/tail slots -> valid node, masked by w=0 below
            unsigned x0 = min((unsigned)i0.x, N_NODES - 1u);
            unsigned x1 = min((unsigned)i0.y, N_NODES - 1u);
            unsigned x2 = min((unsigned)i0.z, N_NODES - 1u);
            unsigned x3 = min((unsigned)i0.w, N_NODES - 1u);
            unsigned x4 = min((unsigned)i1.x, N_NODES - 1u);
            unsigned x5 = min((unsigned)i1.y, N_NODES - 1u);
            unsigned x6 = min((unsigned)i1.z, N_NODES - 1u);
            unsigned x7 = min((unsigned)i1.w, N_NODES - 1u);
            u16x8 r0 = r8[(size_t)x0 * 32 + hl];        // 8 independent 16B row loads
            u16x8 r1 = r8[(size_t)x1 * 32 + hl];
            u16x8 r2 = r8[(size_t)x2 * 32 + hl];
            u16x8 r3 = r8[(size_t)x3 * 32 + hl];
            u16x8 r4 = r8[(size_t)x4 * 32 + hl];
            u16x8 r5 = r8[(size_t)x5 * 32 + hl];
            u16x8 r6 = r8[(size_t)x6 * 32 + hl];
            u16x8 r7 = r8[(size_t)x7 * 32 + hl];
            float w0 = (j + 0 < dg) ? wgt[x0] : 0.f;    // broadcast f32 loads
            float w1 = (j + 1 < dg) ? wgt[x1] : 0.f;
            float w2 = (j + 2 < dg) ? wgt[x2] : 0.f;
            float w3 = (j + 3 < dg) ? wgt[x3] : 0.f;
            float w4 = (j + 4 < dg) ? wgt[x4] : 0.f;
            float w5 = (j + 5 < dg) ? wgt[x5] : 0.f;
            float w6 = (j + 6 < dg) ? wgt[x6] : 0.f;
            float w7 = (j + 7 < dg) ? wgt[x7] : 0.f;
            #pragma unroll
            for (int i = 0; i < 8; ++i) {
                float s = fmaf(w0, b2f(r0[i]), a[i]);
                s = fmaf(w1, b2f(r1[i]), s);
                s = fmaf(w2, b2f(r2[i]), s);
                s = fmaf(w3, b2f(r3[i]), s);
                s = fmaf(w4, b2f(r4[i]), s);
                s = fmaf(w5, b2f(r5[i]), s);
                s = fmaf(w6, b2f(r6[i]), s);
                s = fmaf(w7, b2f(r7[i]), s);
                a[i] = s;
            }
        }

        if (ovfN) {   // correctness-only path; never taken for this graph
            for (uint32_t k = 0; k < ovfN; ++k) {
                uint32_t od = ovf[2 * k], os = ovf[2 * k + 1];
                if (valid && od == (uint32_t)node) {
                    float wv = wgt[os];
                    u16x8 rv = r8[(size_t)os * 32 + hl];
                    #pragma unroll
                    for (int i = 0; i < 8; ++i) a[i] = fmaf(wv, b2f(rv[i]), a[i]);
                }
            }
        }

        short8 o;
        #pragma unroll
        for (int i = 0; i < 8; ++i) o[i] = (short)f2b(di * a[i]);
        // swizzled write: logical chunk hl -> physical chunk hl ^ (row&7)
        *(short8*)((char*)As + nl * 512 + ((hl ^ (nl & 7)) << 4)) = o;
    }
    __syncthreads();

    // ---- phase 2: GEMM, swapped operands ----
    int m = lane & 15, quad = lane >> 4;

    f32x4 acc[4][4];
    #pragma unroll
    for (int mt = 0; mt < 4; ++mt)
        #pragma unroll
        for (int nt = 0; nt < 4; ++nt)
            acc[mt][nt] = (f32x4){0.f, 0.f, 0.f, 0.f};

    #pragma unroll
    for (int ks = 0; ks < 8; ++ks) {          // K = 8 steps x 32
        short8 wf[4], xf[4];
        #pragma unroll
        for (int nt = 0; nt < 4; ++nt)
            wf[nt] = *(const short8*)(Wt + (size_t)(w * 64 + nt * 16 + m) * 256 + ks * 32 + quad * 8);
        #pragma unroll
        for (int mt = 0; mt < 4; ++mt) {
            int rl = mt * 16 + m;
            int ch = (ks * 4 + quad) ^ (rl & 7);
            xf[mt] = *(const short8*)((const char*)As + rl * 512 + (ch << 4));
        }
        #pragma unroll
        for (int mt = 0; mt < 4; ++mt)
            #pragma unroll
            for (int nt = 0; nt < 4; ++nt)
                acc[mt][nt] = __builtin_amdgcn_mfma_f32_16x16x32_bf16(
                    wf[nt], xf[mt], acc[mt][nt], 0, 0, 0);
    }

    // epilogue: D row (quad*4+r) = output col, D col (lane&15) = node
    float4 bv[4];
    #pragma unroll
    for (int nt = 0; nt < 4; ++nt)
        bv[nt] = *(const float4*)(bias + w * 64 + nt * 16 + quad * 4);

    #pragma unroll
    for (int mt = 0; mt < 4; ++mt) {
        int node = rowBase + mt * 16 + m;
        if (node >= N_NODES) continue;
        if (Cf) {
            #pragma unroll
            for (int nt = 0; nt < 4; ++nt) {
                int c = w * 64 + nt * 16 + quad * 4;
                f32x4 v = acc[mt][nt];
                f32x4 o;
                o.x = fmaxf(v[0] + bv[nt].x, 0.f);
                o.y = fmaxf(v[1] + bv[nt].y, 0.f);
                o.z = fmaxf(v[2] + bv[nt].z, 0.f);
                o.w = fmaxf(v[3] + bv[nt].w, 0.f);
                // final output never re-read -> NT store, keep caches for gather rows
                __builtin_nontemporal_store(o, (f32x4*)(Cf + (size_t)node * 256 + c));
            }
        } else {
            #pragma unroll
            for (int nt = 0; nt < 4; ++nt) {
                int c = w * 64 + nt * 16 + quad * 4;
                f32x4 v = acc[mt][nt];
                u16x4 o;   // raw relu, bf16 (layer-2 gather applies weights itself)
                o.x = f2b(fmaxf(v[0] + bv[nt].x, 0.f));
                o.y = f2b(fmaxf(v[1] + bv[nt].y, 0.f));
                o.z = f2b(fmaxf(v[2] + bv[nt].z, 0.f));
                o.w = f2b(fmaxf(v[3] + bv[nt].w, 0.f));
                *(u16x4*)(Cb + (size_t)node * 256 + c) = o;
            }
        }
    }
}

extern "C" void kernel_launch(void* const* d_in, const int* in_sizes, int n_in,
                              void* d_out, int out_size, void* d_ws, size_t ws_size,
                              hipStream_t stream) {
    const int*   edge = (const int*)d_in[0];   // [2][E]: row0 = src, row1 = dst
    const float* x    = (const float*)d_in[1];
    const float* W1   = (const float*)d_in[2];
    const float* b1   = (const float*)d_in[3];
    const float* W2   = (const float*)d_in[4];
    const float* b2   = (const float*)d_in[5];
    float* out = (float*)d_out;

    char* ws = (char*)d_ws;
    uint32_t*       cnt    = (uint32_t*)(ws + 0);
    uint32_t*       ovfCnt = (uint32_t*)(ws + 400000);
    int*            colM   = (int*)     (ws + 400256);
    float*          wgt    = (float*)   (ws + 13200256);
    uint32_t*       ovf    = (uint32_t*)(ws + 13600256);
    unsigned short* Wt1    = (unsigned short*)(ws + 21600256);
    unsigned short* Wt2    = (unsigned short*)(ws + 21731328);
    unsigned short* xs     = (unsigned short*)(ws + 21862400);
    unsigned short* z1s    = (unsigned short*)(ws + 73062400ull);

    const int* src = edge;
    const int* dst = edge + N_EDGES;

    // zero cnt + ovfCnt only (colM no longer needs zeroing: gather clamps)
    hipMemsetAsync(ws, 0, 400256, stream);

    // all heavy preprocessing in one launch: fill || pack || cvt
    k_pre<<<NB_FILL + NB_PACK + NB_CVT, 256, 0, stream>>>(
        src, dst, cnt, ovfCnt, colM, ovf, W1, W2, Wt1, Wt2, x, xs);
    // tiny: per-node weight table
    k_wgt<<<(N_NODES + 255) / 256, 256, 0, stream>>>(cnt, wgt);

    // layer 1: fused gather+GEMM, writes raw relu bf16 z1s
    k_fused<<<(N_NODES + 63) / 64, 256, 0, stream>>>(
        xs, cnt, wgt, ovfCnt, colM, ovf, Wt1, b1, z1s, nullptr);
    // layer 2: fused gather+GEMM, writes fp32 output
    k_fused<<<(N_NODES + 63) / 64, 256, 0, stream>>>(
        z1s, cnt, wgt, ovfCnt, colM, ovf, Wt2, b2, nullptr, out);
}